// Round 1
// baseline (1233.182 us; speedup 1.0000x reference)
//
#include <hip/hip_runtime.h>
#include <math.h>

#define B_ 4
#define N_ 2048
#define D_ 256
#define H_ 8
#define HD_ 32
#define F_ 1024
#define M_ (B_*N_)
#define EPS_ 1e-5f

// ---------------- LayerNorm (one block per row of 256) ----------------
__global__ __launch_bounds__(256) void ln_kernel(const float* __restrict__ x,
        const float* __restrict__ g, const float* __restrict__ be,
        float* __restrict__ out) {
    int row = blockIdx.x;
    int tid = threadIdx.x;
    float v = x[(size_t)row * D_ + tid];
    float s = v, s2 = v * v;
    #pragma unroll
    for (int off = 32; off > 0; off >>= 1) {
        s  += __shfl_down(s,  off, 64);
        s2 += __shfl_down(s2, off, 64);
    }
    __shared__ float ps[4], ps2[4];
    int wid = tid >> 6;
    if ((tid & 63) == 0) { ps[wid] = s; ps2[wid] = s2; }
    __syncthreads();
    float ts  = ps[0] + ps[1] + ps[2] + ps[3];
    float ts2 = ps2[0] + ps2[1] + ps2[2] + ps2[3];
    float mu  = ts * (1.0f / D_);
    float var = ts2 * (1.0f / D_) - mu * mu;
    float r = rsqrtf(var + EPS_);
    out[(size_t)row * D_ + tid] = (v - mu) * r * g[tid] + be[tid];
}

// ---------------- Tiled fp32 GEMM: C = A[M,K] @ W[K,Nc] + bias, epilogues ----
#define MODE_HEAD 0      // write to (B,H,N,HD) layout, +bias
#define MODE_BIAS_RES 1  // +bias +res, row-major
#define MODE_GELU 2      // gelu(acc+bias), row-major

template<int MODE>
__global__ __launch_bounds__(256) void gemm_kernel(
        const float* __restrict__ A, const float* __restrict__ W,
        const float* __restrict__ bias, const float* __restrict__ res,
        float* __restrict__ C, int M, int Nc, int K) {
    __shared__ float As[16][68];
    __shared__ float Bs[16][68];
    int tid = threadIdx.x;
    int m0 = blockIdx.y * 64;
    int n0 = blockIdx.x * 64;
    int ty = tid >> 4, tx = tid & 15;
    float acc[4][4] = {};
    int am = tid >> 2;            // 0..63 : A-tile row
    int ak = (tid & 3) * 4;       // 0,4,8,12 : A-tile k start
    int bk = tid >> 4;            // 0..15 : B-tile k
    int bn = (tid & 15) * 4;      // B-tile col start

    for (int k0 = 0; k0 < K; k0 += 16) {
        float4 av = *(const float4*)&A[(size_t)(m0 + am) * K + k0 + ak];
        float4 bv = *(const float4*)&W[(size_t)(k0 + bk) * Nc + n0 + bn];
        __syncthreads();
        As[ak + 0][am] = av.x; As[ak + 1][am] = av.y;
        As[ak + 2][am] = av.z; As[ak + 3][am] = av.w;
        *(float4*)&Bs[bk][bn] = bv;
        __syncthreads();
        #pragma unroll
        for (int k = 0; k < 16; k++) {
            float4 a4 = *(const float4*)&As[k][ty * 4];
            float4 b4 = *(const float4*)&Bs[k][tx * 4];
            const float* ap = &a4.x;
            const float* bp = &b4.x;
            #pragma unroll
            for (int i = 0; i < 4; i++)
                #pragma unroll
                for (int j = 0; j < 4; j++)
                    acc[i][j] += ap[i] * bp[j];
        }
    }

    #pragma unroll
    for (int i = 0; i < 4; i++) {
        int row = m0 + ty * 4 + i;
        int col0 = n0 + tx * 4;
        float4 o;
        float* op = &o.x;
        #pragma unroll
        for (int j = 0; j < 4; j++) {
            float vacc = acc[i][j] + bias[col0 + j];
            if (MODE == MODE_GELU) {
                vacc = 0.5f * vacc * (1.0f + erff(vacc * 0.70710678118654752f));
            } else if (MODE == MODE_BIAS_RES) {
                vacc += res[(size_t)row * Nc + col0 + j];
            }
            op[j] = vacc;
        }
        if (MODE == MODE_HEAD) {
            int b = row >> 11, n = row & (N_ - 1);
            int h = col0 >> 5, d = col0 & 31;
            *(float4*)&C[((((size_t)b * H_ + h) * N_) + n) * HD_ + d] = o;
        } else {
            *(float4*)&C[(size_t)row * Nc + col0] = o;
        }
    }
}

// ---------------- Flash-style masked attention, fp32, thread-per-q-row ------
__global__ __launch_bounds__(256) void attn_kernel(
        const float* __restrict__ q, const float* __restrict__ k,
        const float* __restrict__ v, const int* __restrict__ adj,
        float* __restrict__ out) {
    int b = blockIdx.z, h = blockIdx.y;
    int tid = threadIdx.x;
    int qrow = blockIdx.x * 256 + tid;
    const float* qp = q + (((size_t)(b * H_ + h)) * N_ + qrow) * HD_;
    float4 qr[8];
    #pragma unroll
    for (int i = 0; i < 8; i++) qr[i] = *(const float4*)&qp[i * 4];
    const int* adjrow = adj + ((size_t)b * N_ + qrow) * N_;
    const float* kbase = k + ((size_t)(b * H_ + h)) * N_ * HD_;
    const float* vbase = v + ((size_t)(b * H_ + h)) * N_ * HD_;
    __shared__ float Ks[64 * HD_];
    __shared__ float Vs[64 * HD_];
    float m = -1e30f, l = 0.f;
    float4 acc[8] = {};

    for (int k0 = 0; k0 < N_; k0 += 64) {
        __syncthreads();
        #pragma unroll
        for (int i = 0; i < 2; i++) {
            int f4 = tid + i * 256;   // 0..511 float4s = 64 rows x 32 floats
            *(float4*)&Ks[f4 * 4] = *(const float4*)&kbase[(size_t)k0 * HD_ + f4 * 4];
            *(float4*)&Vs[f4 * 4] = *(const float4*)&vbase[(size_t)k0 * HD_ + f4 * 4];
        }
        __syncthreads();
        for (int kk = 0; kk < 64; kk++) {
            int a = adjrow[k0 + kk];
            if (a != 0) {
                const float4* kr = (const float4*)&Ks[kk * HD_];
                float s = 0.f;
                #pragma unroll
                for (int i = 0; i < 8; i++) {
                    float4 kv = kr[i];
                    s += qr[i].x * kv.x + qr[i].y * kv.y + qr[i].z * kv.z + qr[i].w * kv.w;
                }
                s *= 0.17677669529663687f;   // 1/sqrt(32)
                float nm = fmaxf(m, s);
                float p  = __expf(s - nm);
                float sc = __expf(m - nm);
                l = l * sc + p;
                const float4* vr = (const float4*)&Vs[kk * HD_];
                #pragma unroll
                for (int i = 0; i < 8; i++) {
                    float4 vv = vr[i];
                    acc[i].x = acc[i].x * sc + p * vv.x;
                    acc[i].y = acc[i].y * sc + p * vv.y;
                    acc[i].z = acc[i].z * sc + p * vv.z;
                    acc[i].w = acc[i].w * sc + p * vv.w;
                }
                m = nm;
            }
        }
    }
    float inv = (l > 0.f) ? 1.0f / l : 0.f;   // all-masked row -> zeros (nan_to_num)
    float* op = out + ((size_t)(b * N_ + qrow)) * D_ + h * HD_;
    #pragma unroll
    for (int i = 0; i < 8; i++) {
        float4 o = acc[i];
        o.x *= inv; o.y *= inv; o.z *= inv; o.w *= inv;
        *(float4*)&op[i * 4] = o;
    }
}

// ---------------- Launch -----------------------------------------------------
extern "C" void kernel_launch(void* const* d_in, const int* in_sizes, int n_in,
                              void* d_out, int out_size, void* d_ws, size_t ws_size,
                              hipStream_t stream) {
    const float* x   = (const float*)d_in[0];
    const int*   adj = (const int*)d_in[1];
    const float* wq  = (const float*)d_in[2];
    const float* bq  = (const float*)d_in[3];
    const float* wk  = (const float*)d_in[4];
    const float* bk  = (const float*)d_in[5];
    const float* wv  = (const float*)d_in[6];
    const float* bv  = (const float*)d_in[7];
    const float* wo  = (const float*)d_in[8];
    const float* bo  = (const float*)d_in[9];
    const float* g1  = (const float*)d_in[10];
    const float* be1 = (const float*)d_in[11];
    const float* g2  = (const float*)d_in[12];
    const float* be2 = (const float*)d_in[13];
    const float* w1  = (const float*)d_in[14];
    const float* b1  = (const float*)d_in[15];
    const float* w2  = (const float*)d_in[16];
    const float* b2  = (const float*)d_in[17];
    float* out = (float*)d_out;
    float* ws  = (float*)d_ws;

    const size_t S = (size_t)M_ * D_;   // 2M floats = 8 MB
    // layout: [0..4S) shared by {xn,q,k,v} then reused by h1 (4S floats)
    float* xn = ws + 0 * S;
    float* qb = ws + 1 * S;
    float* kb = ws + 2 * S;
    float* vb = ws + 3 * S;
    float* ao = ws + 4 * S;
    float* x2 = ws + 5 * S;
    float* hn = ws + 6 * S;
    float* h1 = ws + 0 * S;             // overlays xn/q/k/v (dead by then), 4S floats

    dim3 gD(D_ / 64, M_ / 64);          // (4,128)
    dim3 gF(F_ / 64, M_ / 64);          // (16,128)

    ln_kernel<<<M_, 256, 0, stream>>>(x, g1, be1, xn);
    gemm_kernel<MODE_HEAD><<<gD, 256, 0, stream>>>(xn, wq, bq, nullptr, qb, M_, D_, D_);
    gemm_kernel<MODE_HEAD><<<gD, 256, 0, stream>>>(xn, wk, bk, nullptr, kb, M_, D_, D_);
    gemm_kernel<MODE_HEAD><<<gD, 256, 0, stream>>>(xn, wv, bv, nullptr, vb, M_, D_, D_);
    attn_kernel<<<dim3(N_ / 256, H_, B_), 256, 0, stream>>>(qb, kb, vb, adj, ao);
    gemm_kernel<MODE_BIAS_RES><<<gD, 256, 0, stream>>>(ao, wo, bo, x, x2, M_, D_, D_);
    ln_kernel<<<M_, 256, 0, stream>>>(x2, g2, be2, hn);
    gemm_kernel<MODE_GELU><<<gF, 256, 0, stream>>>(hn, w1, b1, nullptr, h1, M_, F_, D_);
    gemm_kernel<MODE_BIAS_RES><<<gD, 256, 0, stream>>>(h1, w2, b2, x2, out, M_, D_, F_);
}

// Round 2
// 474.148 us; speedup vs baseline: 2.6008x; 2.6008x over previous
//
#include <hip/hip_runtime.h>
#include <math.h>

#define B_ 4
#define N_ 2048
#define D_ 256
#define H_ 8
#define HD_ 32
#define F_ 1024
#define M_ (B_*N_)
#define EPS_ 1e-5f
#define PADW 56

typedef __attribute__((ext_vector_type(8))) short short8;
typedef __attribute__((ext_vector_type(4))) float f32x4;

__device__ inline unsigned short f2bf(float f) {
    union { float f; unsigned u; } x; x.f = f;
    unsigned r = x.u + 0x7fff + ((x.u >> 16) & 1);
    return (unsigned short)(r >> 16);
}

// ---------------- LayerNorm (one block per row of 256) ----------------
__global__ __launch_bounds__(256) void ln_kernel(const float* __restrict__ x,
        const float* __restrict__ g, const float* __restrict__ be,
        float* __restrict__ out) {
    int row = blockIdx.x;
    int tid = threadIdx.x;
    float v = x[(size_t)row * D_ + tid];
    float s = v, s2 = v * v;
    #pragma unroll
    for (int off = 32; off > 0; off >>= 1) {
        s  += __shfl_down(s,  off, 64);
        s2 += __shfl_down(s2, off, 64);
    }
    __shared__ float ps[4], ps2[4];
    int wid = tid >> 6;
    if ((tid & 63) == 0) { ps[wid] = s; ps2[wid] = s2; }
    __syncthreads();
    float ts  = ps[0] + ps[1] + ps[2] + ps[3];
    float ts2 = ps2[0] + ps2[1] + ps2[2] + ps2[3];
    float mu  = ts * (1.0f / D_);
    float var = ts2 * (1.0f / D_) - mu * mu;
    float r = rsqrtf(var + EPS_);
    out[(size_t)row * D_ + tid] = (v - mu) * r * g[tid] + be[tid];
}

// ---------------- adj -> bitmask (1 bit per edge) ----------------
__global__ __launch_bounds__(256) void pack_adj(const int* __restrict__ adj,
        unsigned long long* __restrict__ mask) {
    size_t i = (size_t)blockIdx.x * 256 + threadIdx.x;
    unsigned long long bm = __ballot(adj[i] != 0);
    if ((threadIdx.x & 63) == 0) mask[i >> 6] = bm;
}

// ---------------- Tiled fp32 GEMM: C = A[M,K] @ W[K,Nc] + bias, epilogues ----
#define MODE_HEAD 0      // write bf16 to (B,H,N,HD) layout, +bias
#define MODE_BIAS_RES 1  // +bias +res, row-major f32
#define MODE_GELU 2      // gelu(acc+bias), row-major f32

template<int MODE>
__global__ __launch_bounds__(256) void gemm_kernel(
        const float* __restrict__ A, const float* __restrict__ W,
        const float* __restrict__ bias, const float* __restrict__ res,
        float* __restrict__ C, int M, int Nc, int K) {
    __shared__ float As[16][68];
    __shared__ float Bs[16][68];
    int tid = threadIdx.x;
    int m0 = blockIdx.y * 64;
    int n0 = blockIdx.x * 64;
    int ty = tid >> 4, tx = tid & 15;
    float acc[4][4] = {};
    int am = tid >> 2;
    int ak = (tid & 3) * 4;
    int bk = tid >> 4;
    int bn = (tid & 15) * 4;

    for (int k0 = 0; k0 < K; k0 += 16) {
        float4 av = *(const float4*)&A[(size_t)(m0 + am) * K + k0 + ak];
        float4 bv = *(const float4*)&W[(size_t)(k0 + bk) * Nc + n0 + bn];
        __syncthreads();
        As[ak + 0][am] = av.x; As[ak + 1][am] = av.y;
        As[ak + 2][am] = av.z; As[ak + 3][am] = av.w;
        *(float4*)&Bs[bk][bn] = bv;
        __syncthreads();
        #pragma unroll
        for (int k = 0; k < 16; k++) {
            float4 a4 = *(const float4*)&As[k][ty * 4];
            float4 b4 = *(const float4*)&Bs[k][tx * 4];
            const float* ap = &a4.x;
            const float* bp = &b4.x;
            #pragma unroll
            for (int i = 0; i < 4; i++)
                #pragma unroll
                for (int j = 0; j < 4; j++)
                    acc[i][j] += ap[i] * bp[j];
        }
    }

    #pragma unroll
    for (int i = 0; i < 4; i++) {
        int row = m0 + ty * 4 + i;
        int col0 = n0 + tx * 4;
        float vv[4];
        #pragma unroll
        for (int j = 0; j < 4; j++) {
            float vacc = acc[i][j] + bias[col0 + j];
            if (MODE == MODE_GELU) {
                vacc = 0.5f * vacc * (1.0f + erff(vacc * 0.70710678118654752f));
            } else if (MODE == MODE_BIAS_RES) {
                vacc += res[(size_t)row * Nc + col0 + j];
            }
            vv[j] = vacc;
        }
        if (MODE == MODE_HEAD) {
            int bb = row >> 11, n = row & (N_ - 1);
            int hh = col0 >> 5, d = col0 & 31;
            ushort4 o16;
            o16.x = f2bf(vv[0]); o16.y = f2bf(vv[1]);
            o16.z = f2bf(vv[2]); o16.w = f2bf(vv[3]);
            *(ushort4*)&((unsigned short*)C)[((((size_t)bb * H_ + hh) * N_) + n) * HD_ + d] = o16;
        } else {
            float4 o; o.x = vv[0]; o.y = vv[1]; o.z = vv[2]; o.w = vv[3];
            *(float4*)&C[(size_t)row * Nc + col0] = o;
        }
    }
}

// ---------------- MFMA flash attention -------------------------------------
// block = 4 waves, 64 q-rows of one (b,h); 32-key tiles.
__global__ __launch_bounds__(256) void attn_mfma_kernel(
        const unsigned short* __restrict__ q, const unsigned short* __restrict__ k,
        const unsigned short* __restrict__ v, const unsigned* __restrict__ mask,
        float* __restrict__ out) {
    __shared__ unsigned short K_lds[32 * PADW];
    __shared__ unsigned short Vt_lds[32 * PADW];
    __shared__ unsigned short P_lds[4 * 16 * PADW];
    int b = blockIdx.z, h = blockIdx.y;
    int q0 = blockIdx.x * 64;
    int tid = threadIdx.x;
    int w = tid >> 6, lane = tid & 63;
    int lr = lane & 15, lg = lane >> 4;
    size_t bh = (size_t)(b * H_ + h);
    const unsigned short* qbase = q + bh * N_ * HD_;
    const unsigned short* kbase = k + bh * N_ * HD_;
    const unsigned short* vbase = v + bh * N_ * HD_;

    short8 qf = *(const short8*)&qbase[(size_t)(q0 + w * 16 + lr) * HD_ + lg * 8];

    const unsigned* mrow0 = mask + ((size_t)b * N_ + q0 + w * 16 + lg * 4) * (N_ / 32);

    f32x4 acc0 = {}, acc1 = {};
    f32x4 zero = {};
    float m[4] = {-1e30f, -1e30f, -1e30f, -1e30f};
    float l[4] = {0.f, 0.f, 0.f, 0.f};

    int skrow = tid >> 3;          // 0..31
    int scol  = (tid & 7) * 4;     // 0,4,...,28

    for (int k0 = 0; k0 < N_; k0 += 32) {
        __syncthreads();
        ushort4 kv4 = *(const ushort4*)&kbase[(size_t)(k0 + skrow) * HD_ + scol];
        *(ushort4*)&K_lds[skrow * PADW + scol] = kv4;
        ushort4 vv4 = *(const ushort4*)&vbase[(size_t)(k0 + skrow) * HD_ + scol];
        Vt_lds[(scol + 0) * PADW + skrow] = vv4.x;
        Vt_lds[(scol + 1) * PADW + skrow] = vv4.y;
        Vt_lds[(scol + 2) * PADW + skrow] = vv4.z;
        Vt_lds[(scol + 3) * PADW + skrow] = vv4.w;
        __syncthreads();

        short8 kf0 = *(const short8*)&K_lds[lr * PADW + lg * 8];
        short8 kf1 = *(const short8*)&K_lds[(lr + 16) * PADW + lg * 8];
        f32x4 s0 = __builtin_amdgcn_mfma_f32_16x16x32_bf16(qf, kf0, zero, 0, 0, 0);
        f32x4 s1 = __builtin_amdgcn_mfma_f32_16x16x32_bf16(qf, kf1, zero, 0, 0, 0);

        int kb32 = k0 >> 5;
        unsigned short pw0[4], pw1[4];
        #pragma unroll
        for (int r = 0; r < 4; r++) {
            unsigned mk = mrow0[(size_t)r * (N_ / 32) + kb32];
            float sr0 = s0[r] * 0.17677669529663687f;
            float sr1 = s1[r] * 0.17677669529663687f;
            int b0 = (mk >> lr) & 1;
            int b1 = (mk >> (lr + 16)) & 1;
            sr0 = b0 ? sr0 : -1e30f;
            sr1 = b1 ? sr1 : -1e30f;
            float bm = fmaxf(sr0, sr1);
            bm = fmaxf(bm, __shfl_xor(bm, 1, 64));
            bm = fmaxf(bm, __shfl_xor(bm, 2, 64));
            bm = fmaxf(bm, __shfl_xor(bm, 4, 64));
            bm = fmaxf(bm, __shfl_xor(bm, 8, 64));
            float nm = fmaxf(m[r], bm);
            float sc = __expf(m[r] - nm);
            m[r] = nm;
            float p0 = b0 ? __expf(sr0 - nm) : 0.f;
            float p1 = b1 ? __expf(sr1 - nm) : 0.f;
            float ls = p0 + p1;
            ls += __shfl_xor(ls, 1, 64);
            ls += __shfl_xor(ls, 2, 64);
            ls += __shfl_xor(ls, 4, 64);
            ls += __shfl_xor(ls, 8, 64);
            l[r] = l[r] * sc + ls;
            acc0[r] *= sc;
            acc1[r] *= sc;
            pw0[r] = f2bf(p0);
            pw1[r] = f2bf(p1);
        }
        unsigned pbase = w * 16 * PADW;
        #pragma unroll
        for (int r = 0; r < 4; r++) {
            P_lds[pbase + (lg * 4 + r) * PADW + lr] = pw0[r];
            P_lds[pbase + (lg * 4 + r) * PADW + lr + 16] = pw1[r];
        }
        short8 pf  = *(const short8*)&P_lds[pbase + lr * PADW + lg * 8];
        short8 vf0 = *(const short8*)&Vt_lds[lr * PADW + lg * 8];
        short8 vf1 = *(const short8*)&Vt_lds[(lr + 16) * PADW + lg * 8];
        acc0 = __builtin_amdgcn_mfma_f32_16x16x32_bf16(pf, vf0, acc0, 0, 0, 0);
        acc1 = __builtin_amdgcn_mfma_f32_16x16x32_bf16(pf, vf1, acc1, 0, 0, 0);
    }

    #pragma unroll
    for (int r = 0; r < 4; r++) {
        float inv = l[r] > 0.f ? 1.0f / l[r] : 0.f;
        int row = q0 + w * 16 + lg * 4 + r;
        float* op = out + ((size_t)(b * N_) + row) * D_ + h * HD_;
        op[lr] = acc0[r] * inv;
        op[lr + 16] = acc1[r] * inv;
    }
}

// ---------------- Launch -----------------------------------------------------
extern "C" void kernel_launch(void* const* d_in, const int* in_sizes, int n_in,
                              void* d_out, int out_size, void* d_ws, size_t ws_size,
                              hipStream_t stream) {
    const float* x   = (const float*)d_in[0];
    const int*   adj = (const int*)d_in[1];
    const float* wq  = (const float*)d_in[2];
    const float* bq  = (const float*)d_in[3];
    const float* wk  = (const float*)d_in[4];
    const float* bk  = (const float*)d_in[5];
    const float* wv  = (const float*)d_in[6];
    const float* bv  = (const float*)d_in[7];
    const float* wo  = (const float*)d_in[8];
    const float* bo  = (const float*)d_in[9];
    const float* g1  = (const float*)d_in[10];
    const float* be1 = (const float*)d_in[11];
    const float* g2  = (const float*)d_in[12];
    const float* be2 = (const float*)d_in[13];
    const float* w1  = (const float*)d_in[14];
    const float* b1  = (const float*)d_in[15];
    const float* w2  = (const float*)d_in[16];
    const float* b2  = (const float*)d_in[17];
    float* out = (float*)d_out;
    char* base = (char*)d_ws;

    float* ao           = (float*)(base);                       // 8 MB
    float* x2           = (float*)(base + ((size_t)8 << 20));   // 8 MB
    float* hn           = (float*)(base + ((size_t)16 << 20));  // 8 MB
    unsigned* mask      = (unsigned*)(base + ((size_t)24 << 20)); // 2 MB
    float* xn           = (float*)(base + ((size_t)26 << 20));  // 8 MB
    unsigned short* qb  = (unsigned short*)(base + ((size_t)34 << 20)); // 4 MB
    unsigned short* kb  = (unsigned short*)(base + ((size_t)38 << 20)); // 4 MB
    unsigned short* vb  = (unsigned short*)(base + ((size_t)42 << 20)); // 4 MB
    float* h1buf        = (float*)(base + ((size_t)26 << 20));  // 16 MB overlay (xn/qb/kb dead)

    dim3 gD(D_ / 64, M_ / 64);

    ln_kernel<<<M_, 256, 0, stream>>>(x, g1, be1, xn);
    pack_adj<<<(B_ * N_ * N_) / 256, 256, 0, stream>>>(adj, (unsigned long long*)mask);
    gemm_kernel<MODE_HEAD><<<gD, 256, 0, stream>>>(xn, wq, bq, nullptr, (float*)qb, M_, D_, D_);
    gemm_kernel<MODE_HEAD><<<gD, 256, 0, stream>>>(xn, wk, bk, nullptr, (float*)kb, M_, D_, D_);
    gemm_kernel<MODE_HEAD><<<gD, 256, 0, stream>>>(xn, wv, bv, nullptr, (float*)vb, M_, D_, D_);
    attn_mfma_kernel<<<dim3(N_ / 64, H_, B_), 256, 0, stream>>>(qb, kb, vb, mask, ao);
    gemm_kernel<MODE_BIAS_RES><<<gD, 256, 0, stream>>>(ao, wo, bo, x, x2, M_, D_, D_);
    ln_kernel<<<M_, 256, 0, stream>>>(x2, g2, be2, hn);

    const int MH = M_ / 2;
    dim3 gF2(F_ / 64, MH / 64);
    dim3 gD2(D_ / 64, MH / 64);
    for (int half = 0; half < 2; half++) {
        const float* hnp = hn + (size_t)half * MH * D_;
        const float* x2p = x2 + (size_t)half * MH * D_;
        float* outp = out + (size_t)half * MH * D_;
        gemm_kernel<MODE_GELU><<<gF2, 256, 0, stream>>>(hnp, w1, b1, nullptr, h1buf, MH, F_, D_);
        gemm_kernel<MODE_BIAS_RES><<<gD2, 256, 0, stream>>>(h1buf, w2, b2, x2p, outp, MH, D_, F_);
    }
}

// Round 3
// 273.903 us; speedup vs baseline: 4.5023x; 1.7311x over previous
//
#include <hip/hip_runtime.h>
#include <math.h>

#define B_ 4
#define N_ 2048
#define D_ 256
#define H_ 8
#define HD_ 32
#define F_ 1024
#define M_ (B_*N_)
#define EPS_ 1e-5f
#define PADW 56

typedef __attribute__((ext_vector_type(8))) short short8;
typedef __attribute__((ext_vector_type(4))) float f32x4;

__device__ inline unsigned short f2bf(float f) {
    union { float f; unsigned u; } x; x.f = f;
    unsigned r = x.u + 0x7fff + ((x.u >> 16) & 1);
    return (unsigned short)(r >> 16);
}

__device__ inline void async_copy16(const void* g, void* l) {
    __builtin_amdgcn_global_load_lds(
        (const __attribute__((address_space(1))) void*)g,
        (__attribute__((address_space(3))) void*)l, 16, 0, 0);
}

// ---------------- LayerNorm (one block per row of 256), bf16 or f32 out -----
template<int BF16OUT>
__global__ __launch_bounds__(256) void ln_kernel(const float* __restrict__ x,
        const float* __restrict__ g, const float* __restrict__ be,
        void* __restrict__ out) {
    int row = blockIdx.x;
    int tid = threadIdx.x;
    float v = x[(size_t)row * D_ + tid];
    float s = v, s2 = v * v;
    #pragma unroll
    for (int off = 32; off > 0; off >>= 1) {
        s  += __shfl_down(s,  off, 64);
        s2 += __shfl_down(s2, off, 64);
    }
    __shared__ float ps[4], ps2[4];
    int wid = tid >> 6;
    if ((tid & 63) == 0) { ps[wid] = s; ps2[wid] = s2; }
    __syncthreads();
    float ts  = ps[0] + ps[1] + ps[2] + ps[3];
    float ts2 = ps2[0] + ps2[1] + ps2[2] + ps2[3];
    float mu  = ts * (1.0f / D_);
    float var = ts2 * (1.0f / D_) - mu * mu;
    float r = rsqrtf(var + EPS_);
    float o = (v - mu) * r * g[tid] + be[tid];
    if (BF16OUT) ((unsigned short*)out)[(size_t)row * D_ + tid] = f2bf(o);
    else         ((float*)out)[(size_t)row * D_ + tid] = o;
}

// ---------------- adj -> bitmask (1 bit per edge) ----------------
__global__ __launch_bounds__(256) void pack_adj(const int* __restrict__ adj,
        unsigned long long* __restrict__ mask) {
    size_t i = (size_t)blockIdx.x * 256 + threadIdx.x;
    unsigned long long bm = __ballot(adj[i] != 0);
    if ((threadIdx.x & 63) == 0) mask[i >> 6] = bm;
}

// ---------------- weight convert + transpose: W[K][Nc] f32 -> Wt[Nc][K] bf16 -
__global__ __launch_bounds__(256) void transpose_w(const float* __restrict__ W,
        unsigned short* __restrict__ Wt, int K, int Nc) {
    __shared__ float t[32][33];
    int n0 = blockIdx.x * 32, k0 = blockIdx.y * 32;
    int tx = threadIdx.x & 31, ty = threadIdx.x >> 5;   // 32 x 8
    #pragma unroll
    for (int i = 0; i < 4; i++)
        t[ty + i * 8][tx] = W[(size_t)(k0 + ty + i * 8) * Nc + n0 + tx];
    __syncthreads();
    #pragma unroll
    for (int i = 0; i < 4; i++)
        Wt[(size_t)(n0 + ty + i * 8) * K + k0 + tx] = f2bf(t[tx][ty + i * 8]);
}

// ---------------- bf16 MFMA GEMM: C = A[M,K] @ Bt[Nc,K]^T + bias ------------
// 128x128 tile, 4 waves (2x2), BK=32, global_load_lds w/ XOR-swizzled source.
#define GM_HEAD 0   // scatter bf16 to q/k/v (B,H,N,HD); Nc=768 fused
#define GM_RES  1   // f32 out, + bias + res
#define GM_GELU 2   // bf16 out, gelu(acc+bias)

template<int MODE>
__global__ __launch_bounds__(256) void gemm_mfma(
        const unsigned short* __restrict__ A,
        const unsigned short* __restrict__ Bt,
        const float* __restrict__ bias, const float* __restrict__ bias2,
        const float* __restrict__ bias3, const float* __restrict__ res,
        void* __restrict__ Cout,
        unsigned short* __restrict__ q_out, unsigned short* __restrict__ k_out,
        unsigned short* __restrict__ v_out, int M, int Nc, int K) {
    __shared__ __align__(16) unsigned short Abuf[128 * 32];
    __shared__ __align__(16) unsigned short Bbuf[128 * 32];
    int tid = threadIdx.x, w = tid >> 6, lane = tid & 63;
    int lr = lane & 15, lg = lane >> 4;
    int wy = w >> 1, wx = w & 1;
    int m0 = blockIdx.y * 128, n0 = blockIdx.x * 128;
    f32x4 acc[4][4] = {};

    int srow = lane >> 2;                 // 0..15 within a 16-row issue
    int schunk = lane & 3;

    for (int k0 = 0; k0 < K; k0 += 32) {
        __syncthreads();
        #pragma unroll
        for (int i = 0; i < 2; i++) {
            int ar = w * 32 + i * 16 + srow;
            int ac = schunk ^ ((ar >> 1) & 3);
            async_copy16(A  + (size_t)(m0 + ar) * K + k0 + ac * 8,
                         Abuf + (size_t)(w * 32 + i * 16) * 32);
            async_copy16(Bt + (size_t)(n0 + ar) * K + k0 + ac * 8,
                         Bbuf + (size_t)(w * 32 + i * 16) * 32);
        }
        __syncthreads();

        short8 af[4], bf[4];
        #pragma unroll
        for (int mi = 0; mi < 4; mi++) {
            int r = wy * 64 + mi * 16 + lr;
            int c = lg ^ ((r >> 1) & 3);
            af[mi] = *(const short8*)&Abuf[r * 32 + c * 8];
        }
        #pragma unroll
        for (int ni = 0; ni < 4; ni++) {
            int r = wx * 64 + ni * 16 + lr;
            int c = lg ^ ((r >> 1) & 3);
            bf[ni] = *(const short8*)&Bbuf[r * 32 + c * 8];
        }
        #pragma unroll
        for (int mi = 0; mi < 4; mi++)
            #pragma unroll
            for (int ni = 0; ni < 4; ni++)
                acc[mi][ni] = __builtin_amdgcn_mfma_f32_16x16x32_bf16(
                        af[mi], bf[ni], acc[mi][ni], 0, 0, 0);
    }

    #pragma unroll
    for (int mi = 0; mi < 4; mi++) {
        #pragma unroll
        for (int r = 0; r < 4; r++) {
            int grow = m0 + wy * 64 + mi * 16 + lg * 4 + r;
            #pragma unroll
            for (int ni = 0; ni < 4; ni++) {
                int gcol = n0 + wx * 64 + ni * 16 + lr;
                float val = acc[mi][ni][r];
                if (MODE == GM_HEAD) {
                    int which = gcol >> 8, nn = gcol & 255;
                    const float* bp = which == 0 ? bias : (which == 1 ? bias2 : bias3);
                    val += bp[nn];
                    unsigned short* dst = which == 0 ? q_out : (which == 1 ? k_out : v_out);
                    int bb = grow >> 11, rr = grow & (N_ - 1);
                    int hh = nn >> 5, dd = nn & 31;
                    dst[((((size_t)bb * H_ + hh) * N_) + rr) * HD_ + dd] = f2bf(val);
                } else if (MODE == GM_RES) {
                    val += bias[gcol] + res[(size_t)grow * Nc + gcol];
                    ((float*)Cout)[(size_t)grow * Nc + gcol] = val;
                } else {
                    val += bias[gcol];
                    val = 0.5f * val * (1.0f + erff(val * 0.70710678118654752f));
                    ((unsigned short*)Cout)[(size_t)grow * Nc + gcol] = f2bf(val);
                }
            }
        }
    }
}

// ---------------- MFMA flash attention (bf16 out) ---------------------------
__global__ __launch_bounds__(256) void attn_mfma_kernel(
        const unsigned short* __restrict__ q, const unsigned short* __restrict__ k,
        const unsigned short* __restrict__ v, const unsigned* __restrict__ mask,
        unsigned short* __restrict__ out) {
    __shared__ unsigned short K_lds[32 * PADW];
    __shared__ unsigned short Vt_lds[32 * PADW];
    __shared__ unsigned short P_lds[4 * 16 * PADW];
    int b = blockIdx.z, h = blockIdx.y;
    int q0 = blockIdx.x * 64;
    int tid = threadIdx.x;
    int w = tid >> 6, lane = tid & 63;
    int lr = lane & 15, lg = lane >> 4;
    size_t bh = (size_t)(b * H_ + h);
    const unsigned short* qbase = q + bh * N_ * HD_;
    const unsigned short* kbase = k + bh * N_ * HD_;
    const unsigned short* vbase = v + bh * N_ * HD_;

    short8 qf = *(const short8*)&qbase[(size_t)(q0 + w * 16 + lr) * HD_ + lg * 8];

    const unsigned* mrow0 = mask + ((size_t)b * N_ + q0 + w * 16 + lg * 4) * (N_ / 32);

    f32x4 acc0 = {}, acc1 = {};
    f32x4 zero = {};
    float m[4] = {-1e30f, -1e30f, -1e30f, -1e30f};
    float l[4] = {0.f, 0.f, 0.f, 0.f};

    int skrow = tid >> 3;
    int scol  = (tid & 7) * 4;

    for (int k0 = 0; k0 < N_; k0 += 32) {
        __syncthreads();
        ushort4 kv4 = *(const ushort4*)&kbase[(size_t)(k0 + skrow) * HD_ + scol];
        *(ushort4*)&K_lds[skrow * PADW + scol] = kv4;
        ushort4 vv4 = *(const ushort4*)&vbase[(size_t)(k0 + skrow) * HD_ + scol];
        Vt_lds[(scol + 0) * PADW + skrow] = vv4.x;
        Vt_lds[(scol + 1) * PADW + skrow] = vv4.y;
        Vt_lds[(scol + 2) * PADW + skrow] = vv4.z;
        Vt_lds[(scol + 3) * PADW + skrow] = vv4.w;
        __syncthreads();

        short8 kf0 = *(const short8*)&K_lds[lr * PADW + lg * 8];
        short8 kf1 = *(const short8*)&K_lds[(lr + 16) * PADW + lg * 8];
        f32x4 s0 = __builtin_amdgcn_mfma_f32_16x16x32_bf16(qf, kf0, zero, 0, 0, 0);
        f32x4 s1 = __builtin_amdgcn_mfma_f32_16x16x32_bf16(qf, kf1, zero, 0, 0, 0);

        int kb32 = k0 >> 5;
        unsigned short pw0[4], pw1[4];
        #pragma unroll
        for (int r = 0; r < 4; r++) {
            unsigned mk = mrow0[(size_t)r * (N_ / 32) + kb32];
            float sr0 = s0[r] * 0.17677669529663687f;
            float sr1 = s1[r] * 0.17677669529663687f;
            int b0 = (mk >> lr) & 1;
            int b1 = (mk >> (lr + 16)) & 1;
            sr0 = b0 ? sr0 : -1e30f;
            sr1 = b1 ? sr1 : -1e30f;
            float bm = fmaxf(sr0, sr1);
            bm = fmaxf(bm, __shfl_xor(bm, 1, 64));
            bm = fmaxf(bm, __shfl_xor(bm, 2, 64));
            bm = fmaxf(bm, __shfl_xor(bm, 4, 64));
            bm = fmaxf(bm, __shfl_xor(bm, 8, 64));
            float nm = fmaxf(m[r], bm);
            float sc = __expf(m[r] - nm);
            m[r] = nm;
            float p0 = b0 ? __expf(sr0 - nm) : 0.f;
            float p1 = b1 ? __expf(sr1 - nm) : 0.f;
            float ls = p0 + p1;
            ls += __shfl_xor(ls, 1, 64);
            ls += __shfl_xor(ls, 2, 64);
            ls += __shfl_xor(ls, 4, 64);
            ls += __shfl_xor(ls, 8, 64);
            l[r] = l[r] * sc + ls;
            acc0[r] *= sc;
            acc1[r] *= sc;
            pw0[r] = f2bf(p0);
            pw1[r] = f2bf(p1);
        }
        unsigned pbase = w * 16 * PADW;
        #pragma unroll
        for (int r = 0; r < 4; r++) {
            P_lds[pbase + (lg * 4 + r) * PADW + lr] = pw0[r];
            P_lds[pbase + (lg * 4 + r) * PADW + lr + 16] = pw1[r];
        }
        short8 pf  = *(const short8*)&P_lds[pbase + lr * PADW + lg * 8];
        short8 vf0 = *(const short8*)&Vt_lds[lr * PADW + lg * 8];
        short8 vf1 = *(const short8*)&Vt_lds[(lr + 16) * PADW + lg * 8];
        acc0 = __builtin_amdgcn_mfma_f32_16x16x32_bf16(pf, vf0, acc0, 0, 0, 0);
        acc1 = __builtin_amdgcn_mfma_f32_16x16x32_bf16(pf, vf1, acc1, 0, 0, 0);
    }

    #pragma unroll
    for (int r = 0; r < 4; r++) {
        float inv = l[r] > 0.f ? 1.0f / l[r] : 0.f;
        int row = q0 + w * 16 + lg * 4 + r;
        unsigned short* op = out + ((size_t)(b * N_) + row) * D_ + h * HD_;
        op[lr]      = f2bf(acc0[r] * inv);
        op[lr + 16] = f2bf(acc1[r] * inv);
    }
}

// ---------------- Launch -----------------------------------------------------
extern "C" void kernel_launch(void* const* d_in, const int* in_sizes, int n_in,
                              void* d_out, int out_size, void* d_ws, size_t ws_size,
                              hipStream_t stream) {
    const float* x   = (const float*)d_in[0];
    const int*   adj = (const int*)d_in[1];
    const float* wq  = (const float*)d_in[2];
    const float* bq  = (const float*)d_in[3];
    const float* wk  = (const float*)d_in[4];
    const float* bk  = (const float*)d_in[5];
    const float* wv  = (const float*)d_in[6];
    const float* bv  = (const float*)d_in[7];
    const float* wo  = (const float*)d_in[8];
    const float* bo  = (const float*)d_in[9];
    const float* g1  = (const float*)d_in[10];
    const float* be1 = (const float*)d_in[11];
    const float* g2  = (const float*)d_in[12];
    const float* be2 = (const float*)d_in[13];
    const float* w1  = (const float*)d_in[14];
    const float* b1  = (const float*)d_in[15];
    const float* w2  = (const float*)d_in[16];
    const float* b2  = (const float*)d_in[17];
    float* out = (float*)d_out;
    char* base = (char*)d_ws;

    const size_t MB = (size_t)1 << 20;
    unsigned*       mask   = (unsigned*)(base);                 // 2 MB
    unsigned short* xn     = (unsigned short*)(base + 2*MB);    // 4 MB
    unsigned short* qb     = (unsigned short*)(base + 6*MB);    // 4 MB
    unsigned short* kb     = (unsigned short*)(base + 10*MB);   // 4 MB
    unsigned short* vb     = (unsigned short*)(base + 14*MB);   // 4 MB
    unsigned short* ao     = (unsigned short*)(base + 18*MB);   // 4 MB
    float*          x2     = (float*)(base + 22*MB);            // 8 MB
    unsigned short* hn     = (unsigned short*)(base + 30*MB);   // 4 MB
    unsigned short* h1     = (unsigned short*)(base + 34*MB);   // 16 MB
    unsigned short* wqkvt  = (unsigned short*)(base + 50*MB);   // 768*256*2 = 384 KB
    unsigned short* wot    = (unsigned short*)(base + 50*MB + 394240);   // 128 KB
    unsigned short* w1t    = (unsigned short*)(base + 51*MB);   // 512 KB
    unsigned short* w2t    = (unsigned short*)(base + 51*MB + 524288);   // 512 KB

    pack_adj<<<(B_ * N_ * N_) / 256, 256, 0, stream>>>(adj, (unsigned long long*)mask);
    transpose_w<<<dim3(8, 8),  256, 0, stream>>>(wq, wqkvt,            256, 256);
    transpose_w<<<dim3(8, 8),  256, 0, stream>>>(wk, wqkvt + 256*256,  256, 256);
    transpose_w<<<dim3(8, 8),  256, 0, stream>>>(wv, wqkvt + 512*256,  256, 256);
    transpose_w<<<dim3(8, 8),  256, 0, stream>>>(wo, wot,              256, 256);
    transpose_w<<<dim3(32, 8), 256, 0, stream>>>(w1, w1t,              256, 1024);
    transpose_w<<<dim3(8, 32), 256, 0, stream>>>(w2, w2t,              1024, 256);

    ln_kernel<1><<<M_, 256, 0, stream>>>(x, g1, be1, xn);
    gemm_mfma<GM_HEAD><<<dim3(6, 64), 256, 0, stream>>>(
        xn, wqkvt, bq, bk, bv, nullptr, nullptr, qb, kb, vb, M_, 768, 256);
    attn_mfma_kernel<<<dim3(N_ / 64, H_, B_), 256, 0, stream>>>(qb, kb, vb, mask, ao);
    gemm_mfma<GM_RES><<<dim3(2, 64), 256, 0, stream>>>(
        ao, wot, bo, nullptr, nullptr, x, x2, nullptr, nullptr, nullptr, M_, 256, 256);
    ln_kernel<1><<<M_, 256, 0, stream>>>(x2, g2, be2, hn);
    gemm_mfma<GM_GELU><<<dim3(8, 64), 256, 0, stream>>>(
        hn, w1t, b1, nullptr, nullptr, nullptr, h1, nullptr, nullptr, nullptr, M_, 1024, 256);
    gemm_mfma<GM_RES><<<dim3(2, 64), 256, 0, stream>>>(
        h1, w2t, b2, nullptr, nullptr, x2, out, nullptr, nullptr, nullptr, M_, 256, 1024);
}

// Round 4
// 189.232 us; speedup vs baseline: 6.5168x; 1.4474x over previous
//
#include <hip/hip_runtime.h>
#include <math.h>

#define B_ 4
#define N_ 2048
#define D_ 256
#define H_ 8
#define HD_ 32
#define F_ 1024
#define M_ (B_*N_)
#define EPS_ 1e-5f

typedef __attribute__((ext_vector_type(8))) short short8;
typedef __attribute__((ext_vector_type(4))) float f32x4;

__device__ inline unsigned short f2bf(float f) {
    union { float f; unsigned u; } x; x.f = f;
    unsigned r = x.u + 0x7fff + ((x.u >> 16) & 1);
    return (unsigned short)(r >> 16);
}

__device__ inline void async_copy16(const void* g, void* l) {
    __builtin_amdgcn_global_load_lds(
        (const __attribute__((address_space(1))) void*)g,
        (__attribute__((address_space(3))) void*)l, 16, 0, 0);
}

// ---------------- LayerNorm (one block per row of 256), bf16 out ------------
template<int BF16OUT>
__global__ __launch_bounds__(256) void ln_kernel(const float* __restrict__ x,
        const float* __restrict__ g, const float* __restrict__ be,
        void* __restrict__ out) {
    int row = blockIdx.x;
    int tid = threadIdx.x;
    float v = x[(size_t)row * D_ + tid];
    float s = v, s2 = v * v;
    #pragma unroll
    for (int off = 32; off > 0; off >>= 1) {
        s  += __shfl_down(s,  off, 64);
        s2 += __shfl_down(s2, off, 64);
    }
    __shared__ float ps[4], ps2[4];
    int wid = tid >> 6;
    if ((tid & 63) == 0) { ps[wid] = s; ps2[wid] = s2; }
    __syncthreads();
    float ts  = ps[0] + ps[1] + ps[2] + ps[3];
    float ts2 = ps2[0] + ps2[1] + ps2[2] + ps2[3];
    float mu  = ts * (1.0f / D_);
    float var = ts2 * (1.0f / D_) - mu * mu;
    float r = rsqrtf(var + EPS_);
    float o = (v - mu) * r * g[tid] + be[tid];
    if (BF16OUT) ((unsigned short*)out)[(size_t)row * D_ + tid] = f2bf(o);
    else         ((float*)out)[(size_t)row * D_ + tid] = o;
}

// ---------------- adj -> bitmask (1 bit per edge) ----------------
__global__ __launch_bounds__(256) void pack_adj(const int* __restrict__ adj,
        unsigned long long* __restrict__ mask) {
    size_t i = (size_t)blockIdx.x * 256 + threadIdx.x;
    unsigned long long bm = __ballot(adj[i] != 0);
    if ((threadIdx.x & 63) == 0) mask[i >> 6] = bm;
}

// ---------------- weight convert + transpose: W[K][Nc] f32 -> Wt[Nc][K] bf16 -
__global__ __launch_bounds__(256) void transpose_w(const float* __restrict__ W,
        unsigned short* __restrict__ Wt, int K, int Nc) {
    __shared__ float t[32][33];
    int n0 = blockIdx.x * 32, k0 = blockIdx.y * 32;
    int tx = threadIdx.x & 31, ty = threadIdx.x >> 5;   // 32 x 8
    #pragma unroll
    for (int i = 0; i < 4; i++)
        t[ty + i * 8][tx] = W[(size_t)(k0 + ty + i * 8) * Nc + n0 + tx];
    __syncthreads();
    #pragma unroll
    for (int i = 0; i < 4; i++)
        Wt[(size_t)(n0 + ty + i * 8) * K + k0 + tx] = f2bf(t[tx][ty + i * 8]);
}

// ---------------- bf16 MFMA GEMM: C = A[M,K] @ Bt[Nc,K]^T + bias ------------
#define GM_HEAD 0   // scatter bf16 to q/k/v (B,H,N,HD); Nc=768 fused; q pre-scaled
#define GM_RES  1   // f32 out, + bias + res
#define GM_GELU 2   // bf16 out, gelu(acc+bias)

template<int MODE>
__global__ __launch_bounds__(256) void gemm_mfma(
        const unsigned short* __restrict__ A,
        const unsigned short* __restrict__ Bt,
        const float* __restrict__ bias, const float* __restrict__ bias2,
        const float* __restrict__ bias3, const float* __restrict__ res,
        void* __restrict__ Cout,
        unsigned short* __restrict__ q_out, unsigned short* __restrict__ k_out,
        unsigned short* __restrict__ v_out, int M, int Nc, int K) {
    __shared__ __align__(16) unsigned short Abuf[128 * 32];
    __shared__ __align__(16) unsigned short Bbuf[128 * 32];
    int tid = threadIdx.x, w = tid >> 6, lane = tid & 63;
    int lr = lane & 15, lg = lane >> 4;
    int wy = w >> 1, wx = w & 1;
    int m0 = blockIdx.y * 128, n0 = blockIdx.x * 128;
    f32x4 acc[4][4] = {};

    int srow = lane >> 2;
    int schunk = lane & 3;

    for (int k0 = 0; k0 < K; k0 += 32) {
        __syncthreads();
        #pragma unroll
        for (int i = 0; i < 2; i++) {
            int ar = w * 32 + i * 16 + srow;
            int ac = schunk ^ ((ar >> 1) & 3);
            async_copy16(A  + (size_t)(m0 + ar) * K + k0 + ac * 8,
                         Abuf + (size_t)(w * 32 + i * 16) * 32);
            async_copy16(Bt + (size_t)(n0 + ar) * K + k0 + ac * 8,
                         Bbuf + (size_t)(w * 32 + i * 16) * 32);
        }
        __syncthreads();

        short8 af[4], bf[4];
        #pragma unroll
        for (int mi = 0; mi < 4; mi++) {
            int r = wy * 64 + mi * 16 + lr;
            int c = lg ^ ((r >> 1) & 3);
            af[mi] = *(const short8*)&Abuf[r * 32 + c * 8];
        }
        #pragma unroll
        for (int ni = 0; ni < 4; ni++) {
            int r = wx * 64 + ni * 16 + lr;
            int c = lg ^ ((r >> 1) & 3);
            bf[ni] = *(const short8*)&Bbuf[r * 32 + c * 8];
        }
        #pragma unroll
        for (int mi = 0; mi < 4; mi++)
            #pragma unroll
            for (int ni = 0; ni < 4; ni++)
                acc[mi][ni] = __builtin_amdgcn_mfma_f32_16x16x32_bf16(
                        af[mi], bf[ni], acc[mi][ni], 0, 0, 0);
    }

    #pragma unroll
    for (int mi = 0; mi < 4; mi++) {
        #pragma unroll
        for (int r = 0; r < 4; r++) {
            int grow = m0 + wy * 64 + mi * 16 + lg * 4 + r;
            #pragma unroll
            for (int ni = 0; ni < 4; ni++) {
                int gcol = n0 + wx * 64 + ni * 16 + lr;
                float val = acc[mi][ni][r];
                if (MODE == GM_HEAD) {
                    int which = gcol >> 8, nn = gcol & 255;
                    const float* bp = which == 0 ? bias : (which == 1 ? bias2 : bias3);
                    val += bp[nn];
                    if (which == 0) val *= 0.17677669529663687f;  // fold 1/sqrt(HD) into Q
                    unsigned short* dst = which == 0 ? q_out : (which == 1 ? k_out : v_out);
                    int bb = grow >> 11, rr = grow & (N_ - 1);
                    int hh = nn >> 5, dd = nn & 31;
                    dst[((((size_t)bb * H_ + hh) * N_) + rr) * HD_ + dd] = f2bf(val);
                } else if (MODE == GM_RES) {
                    val += bias[gcol] + res[(size_t)grow * Nc + gcol];
                    ((float*)Cout)[(size_t)grow * Nc + gcol] = val;
                } else {
                    val += bias[gcol];
                    val = 0.5f * val * (1.0f + erff(val * 0.70710678118654752f));
                    ((unsigned short*)Cout)[(size_t)grow * Nc + gcol] = f2bf(val);
                }
            }
        }
    }
}

// ---------------- MFMA flash attention v2: swapped QK^T, KVBLK=64 -----------
// block = 4 waves, 64 q-rows of one (b,h). Lane holds P-row for q = lane&15.
#define VSTR 72   // u16 stride for Vt and P LDS (16B aligned, banks ~2-way)
__global__ __launch_bounds__(256) void attn_mfma2(
        const unsigned short* __restrict__ q, const unsigned short* __restrict__ k,
        const unsigned short* __restrict__ v, const unsigned long long* __restrict__ mask,
        unsigned short* __restrict__ out) {
    __shared__ __align__(16) unsigned short Kb[64 * 32];   // K rows, chunk-swizzled
    __shared__ __align__(16) unsigned short Vt[32 * VSTR]; // V^T [d][k]
    __shared__ __align__(16) unsigned short Pl[64 * VSTR]; // per-wave 16 P rows
    int b = blockIdx.z, h = blockIdx.y;
    int q0 = blockIdx.x * 64;
    int tid = threadIdx.x, w = tid >> 6, lane = tid & 63;
    int lr = lane & 15, lg = lane >> 4;
    size_t bh = (size_t)(b * H_ + h);
    const unsigned short* qbp = q + bh * N_ * HD_;
    const unsigned short* kbp = k + bh * N_ * HD_;
    const unsigned short* vbp = v + bh * N_ * HD_;

    short8 qf = *(const short8*)&qbp[(size_t)(q0 + w * 16 + lr) * HD_ + lg * 8];
    const unsigned long long* mrow = mask + ((size_t)b * N_ + q0 + w * 16 + lr) * (N_ / 64);

    int swz = (lr & 3) ^ ((lr >> 2) & 3);      // K read chunk XOR
    // K staging: row sr = tid>>2, chunk sc = tid&3, inverse-swizzled source
    int sr = tid >> 2, sc = tid & 3;
    int ssw = (sr & 3) ^ ((sr >> 2) & 3);
    const unsigned short* ksrc = kbp + (size_t)sr * HD_ + (sc ^ ssw) * 8;
    unsigned short* kdst = Kb + (size_t)w * 16 * 32;    // wave-uniform; HW adds lane*16B
    // V staging: lane -> k-row, wave -> d-block of 8
    int vk = lane, vd0 = w * 8;
    const unsigned short* vsrc = vbp + (size_t)vk * HD_ + vd0;

    f32x4 acc0 = {}, acc1 = {};
    f32x4 zero = {};
    float m_run = -1e30f, l_run = 0.f;

    for (int t = 0; t < N_ / 64; t++) {
        int k0 = t * 64;
        __syncthreads();
        short8 vreg = *(const short8*)(vsrc + (size_t)k0 * HD_);
        async_copy16(ksrc + (size_t)k0 * HD_, kdst);
        unsigned long long mk = mrow[t];
        #pragma unroll
        for (int i = 0; i < 8; i++)
            Vt[(vd0 + i) * VSTR + vk] = (unsigned short)vreg[i];
        __syncthreads();

        // S^T = K @ Q^T : lane (lr=q, lg) gets s for k = j*16 + lg*4 + r
        f32x4 s[4];
        #pragma unroll
        for (int j = 0; j < 4; j++) {
            short8 kf = *(const short8*)&Kb[(j * 16 + lr) * 32 + ((lg ^ swz) * 8)];
            s[j] = __builtin_amdgcn_mfma_f32_16x16x32_bf16(kf, qf, zero, 0, 0, 0);
        }

        unsigned m01 = (unsigned)(mk >> (lg * 4));
        unsigned m23 = (unsigned)(mk >> (lg * 4 + 32));
        float p[16];
        float bm = -1e30f;
        #pragma unroll
        for (int j = 0; j < 4; j++) {
            unsigned mw = (j < 2) ? m01 : m23;
            #pragma unroll
            for (int r = 0; r < 4; r++) {
                int bit = (mw >> ((j & 1) * 16 + r)) & 1;
                float sv = s[j][r];
                p[j * 4 + r] = bit ? sv : -1e30f;
                bm = fmaxf(bm, p[j * 4 + r]);
            }
        }
        bm = fmaxf(bm, __shfl_xor(bm, 16, 64));
        bm = fmaxf(bm, __shfl_xor(bm, 32, 64));
        float nm = fmaxf(m_run, bm);
        if (__any(nm - m_run > 8.0f)) {          // defer-max (T13)
            float sc_ = __expf(m_run - nm);
            m_run = nm;
            l_run *= sc_;
            #pragma unroll
            for (int r = 0; r < 4; r++) {
                float scr = __shfl(sc_, lg * 4 + r, 64);
                acc0[r] *= scr;
                acc1[r] *= scr;
            }
        }
        float ls = 0.f;
        #pragma unroll
        for (int i = 0; i < 16; i++) {
            float pv = (p[i] > -1e29f) ? __expf(p[i] - m_run) : 0.f;
            p[i] = pv;
            ls += pv;
        }
        ls += __shfl_xor(ls, 16, 64);
        ls += __shfl_xor(ls, 32, 64);
        l_run += ls;

        // pack P -> wave-private LDS rows [q=lr][k], vectorized b64 writes
        unsigned pbase = (w * 16 + lr) * VSTR;
        #pragma unroll
        for (int j = 0; j < 4; j++) {
            ushort4 pq;
            pq.x = f2bf(p[j * 4 + 0]); pq.y = f2bf(p[j * 4 + 1]);
            pq.z = f2bf(p[j * 4 + 2]); pq.w = f2bf(p[j * 4 + 3]);
            *(ushort4*)&Pl[pbase + j * 16 + lg * 4] = pq;
        }
        short8 pf0 = *(const short8*)&Pl[pbase + lg * 8];
        short8 pf1 = *(const short8*)&Pl[pbase + 32 + lg * 8];
        short8 vf00 = *(const short8*)&Vt[lr * VSTR + lg * 8];
        short8 vf01 = *(const short8*)&Vt[lr * VSTR + 32 + lg * 8];
        short8 vf10 = *(const short8*)&Vt[(lr + 16) * VSTR + lg * 8];
        short8 vf11 = *(const short8*)&Vt[(lr + 16) * VSTR + 32 + lg * 8];
        acc0 = __builtin_amdgcn_mfma_f32_16x16x32_bf16(pf0, vf00, acc0, 0, 0, 0);
        acc0 = __builtin_amdgcn_mfma_f32_16x16x32_bf16(pf1, vf01, acc0, 0, 0, 0);
        acc1 = __builtin_amdgcn_mfma_f32_16x16x32_bf16(pf0, vf10, acc1, 0, 0, 0);
        acc1 = __builtin_amdgcn_mfma_f32_16x16x32_bf16(pf1, vf11, acc1, 0, 0, 0);
    }

    float linv = (l_run > 0.f) ? 1.0f / l_run : 0.f;   // lane-space: q = lr
    #pragma unroll
    for (int r = 0; r < 4; r++) {
        float ir = __shfl(linv, lg * 4 + r, 64);
        int row = q0 + w * 16 + lg * 4 + r;
        unsigned short* op = out + ((size_t)(b * N_) + row) * D_ + h * HD_;
        op[lr]      = f2bf(acc0[r] * ir);
        op[lr + 16] = f2bf(acc1[r] * ir);
    }
}

// ---------------- Launch -----------------------------------------------------
extern "C" void kernel_launch(void* const* d_in, const int* in_sizes, int n_in,
                              void* d_out, int out_size, void* d_ws, size_t ws_size,
                              hipStream_t stream) {
    const float* x   = (const float*)d_in[0];
    const int*   adj = (const int*)d_in[1];
    const float* wq  = (const float*)d_in[2];
    const float* bq  = (const float*)d_in[3];
    const float* wk  = (const float*)d_in[4];
    const float* bk  = (const float*)d_in[5];
    const float* wv  = (const float*)d_in[6];
    const float* bv  = (const float*)d_in[7];
    const float* wo  = (const float*)d_in[8];
    const float* bo  = (const float*)d_in[9];
    const float* g1  = (const float*)d_in[10];
    const float* be1 = (const float*)d_in[11];
    const float* g2  = (const float*)d_in[12];
    const float* be2 = (const float*)d_in[13];
    const float* w1  = (const float*)d_in[14];
    const float* b1  = (const float*)d_in[15];
    const float* w2  = (const float*)d_in[16];
    const float* b2  = (const float*)d_in[17];
    float* out = (float*)d_out;
    char* base = (char*)d_ws;

    const size_t MB = (size_t)1 << 20;
    unsigned long long* mask = (unsigned long long*)(base);     // 2 MB
    unsigned short* xn     = (unsigned short*)(base + 2*MB);    // 4 MB
    unsigned short* qb     = (unsigned short*)(base + 6*MB);    // 4 MB
    unsigned short* kb     = (unsigned short*)(base + 10*MB);   // 4 MB
    unsigned short* vb     = (unsigned short*)(base + 14*MB);   // 4 MB
    unsigned short* ao     = (unsigned short*)(base + 18*MB);   // 4 MB
    float*          x2     = (float*)(base + 22*MB);            // 8 MB
    unsigned short* hn     = (unsigned short*)(base + 30*MB);   // 4 MB
    unsigned short* h1     = (unsigned short*)(base + 34*MB);   // 16 MB
    unsigned short* wqkvt  = (unsigned short*)(base + 50*MB);   // 384 KB
    unsigned short* wot    = (unsigned short*)(base + 50*MB + 394240);   // 128 KB
    unsigned short* w1t    = (unsigned short*)(base + 51*MB);   // 512 KB
    unsigned short* w2t    = (unsigned short*)(base + 51*MB + 524288);   // 512 KB

    pack_adj<<<(B_ * N_ * N_) / 256, 256, 0, stream>>>(adj, mask);
    transpose_w<<<dim3(8, 8),  256, 0, stream>>>(wq, wqkvt,            256, 256);
    transpose_w<<<dim3(8, 8),  256, 0, stream>>>(wk, wqkvt + 256*256,  256, 256);
    transpose_w<<<dim3(8, 8),  256, 0, stream>>>(wv, wqkvt + 512*256,  256, 256);
    transpose_w<<<dim3(8, 8),  256, 0, stream>>>(wo, wot,              256, 256);
    transpose_w<<<dim3(32, 8), 256, 0, stream>>>(w1, w1t,              256, 1024);
    transpose_w<<<dim3(8, 32), 256, 0, stream>>>(w2, w2t,              1024, 256);

    ln_kernel<1><<<M_, 256, 0, stream>>>(x, g1, be1, xn);
    gemm_mfma<GM_HEAD><<<dim3(6, 64), 256, 0, stream>>>(
        xn, wqkvt, bq, bk, bv, nullptr, nullptr, qb, kb, vb, M_, 768, 256);
    attn_mfma2<<<dim3(N_ / 64, H_, B_), 256, 0, stream>>>(qb, kb, vb, mask, ao);
    gemm_mfma<GM_RES><<<dim3(2, 64), 256, 0, stream>>>(
        ao, wot, bo, nullptr, nullptr, x, x2, nullptr, nullptr, nullptr, M_, 256, 256);
    ln_kernel<1><<<M_, 256, 0, stream>>>(x2, g2, be2, hn);
    gemm_mfma<GM_GELU><<<dim3(8, 64), 256, 0, stream>>>(
        hn, w1t, b1, nullptr, nullptr, nullptr, h1, nullptr, nullptr, nullptr, M_, 1024, 256);
    gemm_mfma<GM_RES><<<dim3(2, 64), 256, 0, stream>>>(
        h1, w2t, b2, nullptr, nullptr, x2, out, nullptr, nullptr, nullptr, M_, 256, 1024);
}